// Round 16
// baseline (521.747 us; speedup 1.0000x reference)
//
#include <hip/hip_runtime.h>
#include <math.h>

#define H 16
#define S 2048
#define D 64
#define SCALEQK 0.125f
#define CH 256

typedef __attribute__((ext_vector_type(4))) float f32x4;
typedef __attribute__((ext_vector_type(8))) short bf16x8;
typedef __attribute__((ext_vector_type(8))) _Float16 f16x8;
typedef __attribute__((ext_vector_type(4))) _Float16 f16x4;
typedef __attribute__((ext_vector_type(2))) _Float16 f16x2;

__device__ inline float h2f(unsigned short b) {
    _Float16 h; __builtin_memcpy(&h, &b, 2); return (float)h;
}
__device__ inline unsigned short f2h(float x) {
    _Float16 h = (_Float16)x; unsigned short b; __builtin_memcpy(&b, &h, 2); return b;
}
__device__ inline unsigned int pack2h(float a, float b) {
    return (unsigned int)f2h(a) | ((unsigned int)f2h(b) << 16);
}

// dot2: c += a.lo*b.lo + a.hi*b.hi with f16 operands, f32 accumulate
__device__ inline float fdot2f(unsigned int a, unsigned int b, float c) {
#if __has_builtin(__builtin_amdgcn_fdot2)
    f16x2 av, bv;
    __builtin_memcpy(&av, &a, 4);
    __builtin_memcpy(&bv, &b, 4);
    return __builtin_amdgcn_fdot2(av, bv, c, false);
#else
    return c + h2f((unsigned short)(a & 0xffff)) * h2f((unsigned short)(b & 0xffff))
             + h2f((unsigned short)(a >> 16))    * h2f((unsigned short)(b >> 16));
#endif
}

// split f32 -> bf16 hi + bf16 lo (residual), rne; packed into two uint4 (8 elems)
__device__ inline void stage_hilo(float4 a, float4 b, uint4* vh, uint4* vl) {
    float xs[8] = {a.x, a.y, a.z, a.w, b.x, b.y, b.z, b.w};
    unsigned int hh[8], ll[8];
#pragma unroll
    for (int j = 0; j < 8; ++j) {
        unsigned int u = __float_as_uint(xs[j]);
        unsigned int h = (u + 0x7fffu + ((u >> 16) & 1u)) >> 16;
        float r = xs[j] - __uint_as_float(h << 16);
        unsigned int u2 = __float_as_uint(r);
        hh[j] = h;
        ll[j] = (u2 + 0x7fffu + ((u2 >> 16) & 1u)) >> 16;
    }
    uint4 h4, l4;
    h4.x = hh[0] | (hh[1] << 16); h4.y = hh[2] | (hh[3] << 16);
    h4.z = hh[4] | (hh[5] << 16); h4.w = hh[6] | (hh[7] << 16);
    l4.x = ll[0] | (ll[1] << 16); l4.y = ll[2] | (ll[3] << 16);
    l4.z = ll[4] | (ll[5] << 16); l4.w = ll[6] | (ll[7] << 16);
    *vh = h4; *vl = l4;
}

__device__ inline void online_upd(float& m, float& l, float x) {
    if (x > m) { l = l * __expf(m - x) + 1.f; m = x; }
    else       { l += __expf(x - m); }
}

// ---------------------------------------------------------------------------
// K_cvt: f32 src -> (hi, lo) bf16 split arrays, optional scale. 8 elems/thread.
__global__ __launch_bounds__(256) void mta_cvt_kernel(const float* __restrict__ src,
                                                      unsigned short* __restrict__ hi,
                                                      unsigned short* __restrict__ lo,
                                                      float scale, int n8) {
    int i = blockIdx.x * 256 + threadIdx.x;
    int stride = gridDim.x * 256;
    for (; i < n8; i += stride) {
        const float* p = src + (size_t)i * 8;
        float4 a = *(const float4*)p;
        float4 b = *(const float4*)(p + 4);
        a.x *= scale; a.y *= scale; a.z *= scale; a.w *= scale;
        b.x *= scale; b.y *= scale; b.z *= scale; b.w *= scale;
        uint4 vh, vl; stage_hilo(a, b, &vh, &vl);
        *(uint4*)&hi[(size_t)i * 8] = vh;
        *(uint4*)&lo[(size_t)i * 8] = vl;
    }
}

// K_vt: xv[f][k][d] f32 -> vt[f][d][k] f16, 64x64 LDS-tiled transpose.
__global__ __launch_bounds__(256) void mta_vt_kernel(const float* __restrict__ xv,
                                                     unsigned short* __restrict__ vt) {
    const int kt = blockIdx.x, f = blockIdx.y;
    const int tid = threadIdx.x;
    __shared__ unsigned short lt[64][65];
#pragma unroll
    for (int i = 0; i < 16; ++i) {
        int idx = tid + i * 256;
        int r = idx >> 6, c = idx & 63;
        lt[r][c] = f2h(xv[((size_t)f * S + kt * 64 + r) * D + c]);
    }
    __syncthreads();
#pragma unroll
    for (int i = 0; i < 16; ++i) {
        int idx = tid + i * 256;
        int d = idx >> 6, k = idx & 63;
        vt[((size_t)f * D + d) * S + kt * 64 + k] = lt[k][d];
    }
}

// ---------------------------------------------------------------------------
// K_gemm: raw scores per head, 64q x 64k tile, split-bf16 (hi*hi+hi*lo+lo*hi),
// causal-zeroed, written f16 to R[h][lrow][k]. lrow 0 == global row qs-64.
__global__ __launch_bounds__(256) void mta_gemm_kernel(
        const unsigned short* __restrict__ qhi, const unsigned short* __restrict__ qlo,
        const unsigned short* __restrict__ khi, const unsigned short* __restrict__ klo,
        unsigned short* __restrict__ R, int qs, int SQ) {
    const int kt = blockIdx.x, qt = blockIdx.y, h = blockIdx.z;
    const int q0 = qs - 64 + qt * 64;
    const int k0 = kt * 64;
    if (k0 > q0 + 68) return;
    const int tid = threadIdx.x;
    const int SQ64 = SQ + 64;

    __shared__ unsigned short Qs[2][64][72];   // [hi/lo][row][col]
    __shared__ unsigned short Ks[2][64][72];
    __shared__ unsigned short Ro[64][72];

    {   // stage: each thread 16 cols of one row for Q and K (hi+lo)
        int r = tid >> 2, d = (tid & 3) * 16;
        int gq = q0 + r;
        uint4 z = {0u, 0u, 0u, 0u};
        uint4 a0 = z, a1 = z, b0 = z, b1 = z;
        if (gq >= 0) {
            size_t off = ((size_t)h * S + gq) * D + d;
            a0 = *(const uint4*)&qhi[off]; a1 = *(const uint4*)&qhi[off + 8];
            b0 = *(const uint4*)&qlo[off]; b1 = *(const uint4*)&qlo[off + 8];
        }
        *(uint4*)&Qs[0][r][d] = a0; *(uint4*)&Qs[0][r][d + 8] = a1;
        *(uint4*)&Qs[1][r][d] = b0; *(uint4*)&Qs[1][r][d + 8] = b1;
        size_t offk = ((size_t)h * S + (k0 + r)) * D + d;
        uint4 c0 = *(const uint4*)&khi[offk];
        uint4 c1 = *(const uint4*)&khi[offk + 8];
        uint4 d0 = *(const uint4*)&klo[offk];
        uint4 d1 = *(const uint4*)&klo[offk + 8];
        *(uint4*)&Ks[0][r][d] = c0; *(uint4*)&Ks[0][r][d + 8] = c1;
        *(uint4*)&Ks[1][r][d] = d0; *(uint4*)&Ks[1][r][d + 8] = d1;
    }
    __syncthreads();

    const int w = tid >> 6, lane = tid & 63;
    const int wr = w >> 1, wc = w & 1;
    const int lr = lane & 15, lk = lane >> 4;

    f32x4 acc[2][2];
#pragma unroll
    for (int mi = 0; mi < 2; ++mi)
#pragma unroll
        for (int ni = 0; ni < 2; ++ni) acc[mi][ni] = (f32x4){0.f, 0.f, 0.f, 0.f};

#pragma unroll
    for (int ks = 0; ks < 2; ++ks) {
        int db = ks * 32 + lk * 8;
#pragma unroll
        for (int mi = 0; mi < 2; ++mi) {
            bf16x8 ah = *(const bf16x8*)&Qs[0][wr * 32 + mi * 16 + lr][db];
            bf16x8 al = *(const bf16x8*)&Qs[1][wr * 32 + mi * 16 + lr][db];
#pragma unroll
            for (int ni = 0; ni < 2; ++ni) {
                bf16x8 bh = *(const bf16x8*)&Ks[0][wc * 32 + ni * 16 + lr][db];
                bf16x8 bl = *(const bf16x8*)&Ks[1][wc * 32 + ni * 16 + lr][db];
                acc[mi][ni] = __builtin_amdgcn_mfma_f32_16x16x32_bf16(ah, bh, acc[mi][ni], 0, 0, 0);
                acc[mi][ni] = __builtin_amdgcn_mfma_f32_16x16x32_bf16(ah, bl, acc[mi][ni], 0, 0, 0);
                acc[mi][ni] = __builtin_amdgcn_mfma_f32_16x16x32_bf16(al, bh, acc[mi][ni], 0, 0, 0);
            }
        }
    }

    // causal-zero + pack to Ro (f16)
#pragma unroll
    for (int mi = 0; mi < 2; ++mi)
#pragma unroll
        for (int ni = 0; ni < 2; ++ni)
#pragma unroll
            for (int i = 0; i < 4; ++i) {
                int row = wr * 32 + mi * 16 + lk * 4 + i;
                int col = wc * 32 + ni * 16 + lr;
                int gq = q0 + row, gk = k0 + col;
                Ro[row][col] = f2h((gk <= gq) ? acc[mi][ni][i] : 0.f);
            }
    __syncthreads();

    // coalesced global write: 64 rows x 128B
#pragma unroll
    for (int ii = 0; ii < 2; ++ii) {
        int idx = tid + ii * 256;
        int row = idx >> 3, c8 = (idx & 7) * 8;
        int lrow = qt * 64 + row;
        *(uint4*)&R[((size_t)h * SQ64 + lrow) * S + k0 + c8] = *(const uint4*)&Ro[row][c8];
    }
}

// ---------------------------------------------------------------------------
// K_convmix v5: f16 raw staging (no cvt), conv via v_dot2_f32_f16,
// 2-head phases (8 barriers), MFMA head-mix epilogue. 16q x 64k tile.
__global__ __launch_bounds__(256) void mta_convmix_kernel(
        const unsigned short* __restrict__ R,
        const float* __restrict__ w_pre, const float* __restrict__ w_psm,
        unsigned short* __restrict__ sc, int qs, int SQ) {
    const int kc = blockIdx.x, qt = blockIdx.y;
    const int q0 = qs - 16 + qt * 16;   // qt==0 is the stripe halo tile
    const int k0 = kc * 64;
    if (k0 > q0 + 15) return;
    const int tid = threadIdx.x;
    const int SQ64 = SQ + 64;

    // f16 cols 0..79 map to global cols k0-16 .. k0+63; row padded to 88 f16
    __shared__ unsigned short raw_u16[2][2][21][88];   // [buf][tile-in-phase][row][col]
    __shared__ unsigned short co[1024][16];            // [pixel][h^(x<<2)]
    __shared__ unsigned int wpk[16][6][6];             // f16-pair packed conv weights
    __shared__ unsigned short wpsmf[16][16];           // f16 W[g][h]

    for (int idx = tid; idx < 576; idx += 256) {
        int h = idx / 36, i2 = (idx % 36) / 6, ip = idx % 6;
        float w0 = w_pre[h * 66 + i2 * 11 + ip * 2];
        float w1 = (ip < 5) ? w_pre[h * 66 + i2 * 11 + ip * 2 + 1] : 0.f;
        wpk[h][i2][ip] = pack2h(w0, w1);
    }
    wpsmf[tid >> 4][tid & 15] = f2h(w_psm[tid]);

    const int ql = tid & 15;            // output row
    const int kb = (tid >> 4) * 4;      // output col group (4 cols)

    // staging map: 210 uint4 loads (21 rows x 10 chunks of 8 f16)
    const int sr = tid / 10, sc8 = tid % 10;
    const bool sact = (tid < 210);
    const bool sval = sact && (k0 + sc8 * 8 >= 16);     // global col >= 0
    const size_t srow_off = (size_t)(qt * 16 + sr + 43) * S + (k0 - 16 + sc8 * 8);

    uint4 sA = {0u, 0u, 0u, 0u}, sB = {0u, 0u, 0u, 0u};

#define LOADC(hh, dst) do { \
        if (sval) dst = *(const uint4*)&R[(size_t)(hh) * SQ64 * S + srow_off]; \
        else { dst.x = 0u; dst.y = 0u; dst.z = 0u; dst.w = 0u; } \
    } while (0)

#define WRITEC(bb, tt, src) do { if (sact) { \
        *(uint4*)&raw_u16[bb][tt][sr][sc8 * 8] = src; } \
    } while (0)

#define CONVC(hh, bb, tt) do { \
        float c0_ = 0.f, c1_ = 0.f, c2_ = 0.f, c3_ = 0.f; \
        _Pragma("unroll") \
        for (int i2_ = 0; i2_ < 6; ++i2_) { \
            const unsigned int* rp_ = \
                (const unsigned int*)&raw_u16[bb][tt][ql + i2_][0] + (kb / 2 + 3); \
            unsigned int P_[7]; \
            _Pragma("unroll") \
            for (int i_ = 0; i_ < 7; ++i_) P_[i_] = rp_[i_]; \
            unsigned int Sv_[6]; \
            _Pragma("unroll") \
            for (int i_ = 0; i_ < 6; ++i_) Sv_[i_] = (P_[i_] >> 16) | (P_[i_ + 1] << 16); \
            unsigned int T_ = P_[6] >> 16; \
            const unsigned int* wp_ = &wpk[hh][i2_][0]; \
            _Pragma("unroll") \
            for (int i_ = 0; i_ < 6; ++i_) { \
                unsigned int w_ = wp_[i_]; \
                c0_ = fdot2f(w_, P_[i_], c0_); \
                c1_ = fdot2f(w_, Sv_[i_], c1_); \
                c2_ = fdot2f(w_, P_[i_ + 1], c2_); \
                c3_ = fdot2f(w_, (i_ < 5) ? Sv_[i_ + 1] : T_, c3_); \
            } \
        } \
        { float cc_[4] = {c0_, c1_, c2_, c3_}; \
          int p0_ = ql * 64 + kb; \
          _Pragma("unroll") \
          for (int j_ = 0; j_ < 4; ++j_) { \
              int pp_ = p0_ + j_; \
              int x_ = ((pp_ >> 2) ^ (pp_ >> 6)) & 3; \
              co[pp_][(hh) ^ (x_ << 2)] = f2h(cc_[j_]); } } \
    } while (0)

    LOADC(0, sA);
    LOADC(1, sB);
    WRITEC(0, 0, sA);
    WRITEC(0, 1, sB);
    __syncthreads();
    for (int ph = 0; ph < 8; ++ph) {
        int bb = ph & 1;
        if (ph < 7) { LOADC(2 * ph + 2, sA); LOADC(2 * ph + 3, sB); }
        CONVC(2 * ph,     bb, 0);
        CONVC(2 * ph + 1, bb, 1);
        if (ph < 7) { WRITEC(bb ^ 1, 0, sA); WRITEC(bb ^ 1, 1, sB); }
        __syncthreads();        // last iteration: co complete before mix
    }
#undef LOADC
#undef WRITEC
#undef CONVC

    // head-mix: out[g][p] = sum_h W[g][h] * co[p][h], one MFMA per 16-pixel tile
    const int lane = tid & 63, wv = tid >> 6;
    const int hg = lane >> 4;
#if __has_builtin(__builtin_amdgcn_mfma_f32_16x16x16f16)
    f16x4 afrag = *(const f16x4*)&wpsmf[lane & 15][hg * 4];
    for (int t = wv; t < 64; t += 4) {
        int p = t * 16 + (lane & 15);
        int x = ((p >> 2) ^ (p >> 6)) & 3;
        f16x4 bfrag = *(const f16x4*)&co[p][(hg ^ x) << 2];
        f32x4 d = {0.f, 0.f, 0.f, 0.f};
        d = __builtin_amdgcn_mfma_f32_16x16x16f16(afrag, bfrag, d, 0, 0, 0);
        int qq = q0 + (p >> 6);
        int kk = k0 + (p & 63);
        int srow = qt * 16 + (p >> 6);
#pragma unroll
        for (int i = 0; i < 4; ++i) {
            int g = hg * 4 + i;
            sc[((size_t)(g * (SQ + 16) + srow)) * S + kk] =
                f2h((kk <= qq) ? d[i] : 0.f);
        }
    }
#else
    // VALU fallback (correctness path)
    for (int t = wv; t < 64; t += 4) {
        int p = t * 16 + (lane & 15);
        int x = ((p >> 2) ^ (p >> 6)) & 3;
        float ch[16];
#pragma unroll
        for (int a = 0; a < 4; ++a) {
            f16x4 b4 = *(const f16x4*)&co[p][(a ^ x) << 2];
#pragma unroll
            for (int tt = 0; tt < 4; ++tt) ch[a * 4 + tt] = (float)b4[tt];
        }
        int qq = q0 + (p >> 6);
        int kk = k0 + (p & 63);
        int srow = qt * 16 + (p >> 6);
#pragma unroll
        for (int i = 0; i < 4; ++i) {
            int g = hg * 4 + i;
            float s = 0.f;
#pragma unroll
            for (int hh = 0; hh < 16; ++hh) s += h2f(wpsmf[g][hh]) * ch[hh];
            sc[((size_t)(g * (SQ + 16) + srow)) * S + kk] =
                f2h((kk <= qq) ? s : 0.f);
        }
    }
#endif
}

// ---------------------------------------------------------------------------
// Stats: per (g,q) row of the stripe, m = max, l = sum exp(x-m) over k<=q.
__global__ __launch_bounds__(256) void mta_rowstats_kernel(
        const unsigned short* __restrict__ sc,
        float* __restrict__ mrow, float* __restrict__ rlrow, int qs, int SQ) {
    int row = blockIdx.x * 4 + (threadIdx.x >> 6);
    int lane = threadIdx.x & 63;
    int g = row / SQ, qq = row % SQ;
    int q = qs + qq;
    const unsigned short* rp = sc + ((size_t)(g * (SQ + 16) + qq + 16)) * S;

    float v[32];
#pragma unroll
    for (int it = 0; it < 4; ++it) {
        int kbase = it * 512 + lane * 8;
        if (it * 512 <= q) {
            uint4 u = *(const uint4*)&rp[kbase];
            unsigned int ws[4] = {u.x, u.y, u.z, u.w};
#pragma unroll
            for (int j = 0; j < 4; ++j) {
                float x0 = h2f((unsigned short)(ws[j] & 0xffff));
                float x1 = h2f((unsigned short)(ws[j] >> 16));
                v[it * 8 + 2 * j]     = (kbase + 2 * j     <= q) ? x0 : -INFINITY;
                v[it * 8 + 2 * j + 1] = (kbase + 2 * j + 1 <= q) ? x1 : -INFINITY;
            }
        } else {
#pragma unroll
            for (int j = 0; j < 8; ++j) v[it * 8 + j] = -INFINITY;
        }
    }
    float m = -INFINITY;
#pragma unroll
    for (int j = 0; j < 32; ++j) m = fmaxf(m, v[j]);
#pragma unroll
    for (int off = 1; off < 64; off <<= 1) m = fmaxf(m, __shfl_xor(m, off));
    float l = 0.f;
#pragma unroll
    for (int j = 0; j < 32; ++j) l += __expf(v[j] - m);
#pragma unroll
    for (int off = 1; off < 64; off <<= 1) l += __shfl_xor(l, off);
    if (lane == 0) { mrow[g * S + q] = m; rlrow[g * S + q] = 1.f / l; }
}

// ---------------------------------------------------------------------------
// Pass 2 (r12 version): probs = exp(sc-m)/l, 3x3 conv via dot2,
// w_posm mix via dot2 on packed f16 pairs, MFMA PV. 2 barriers per k-step.
__global__ __launch_bounds__(256, 3) void mta_out2_kernel(
        const unsigned short* __restrict__ sc,
        const float* __restrict__ mrow, const float* __restrict__ rlrow,
        const unsigned short* __restrict__ vt,
        const float* __restrict__ w_post, const float* __restrict__ w_posm,
        float* __restrict__ out, int qs, int SQ) {
    const int qt = blockIdx.x, kc = blockIdx.y;
    const int q0 = qs + qt * 16;
    const int kstart = kc * CH;
    if (kstart > q0 + 15) return;
    const int kend = min(kstart + CH, q0 + 16);
    const int tid = threadIdx.x;

    __shared__ unsigned short ps[16][18][36];
    __shared__ unsigned short pm2[16][16][40];
    __shared__ float mst[16][18], rst[16][18];
    __shared__ unsigned int wpostp[16][3];   // f16 pair (w0,w1) per conv row
    __shared__ float wpost2f[16][3];         // w2 per conv row (f32)
    __shared__ unsigned int wposmp[16][8];   // w_posm f16 pairs over g

    if (tid < 48) {
        int g = tid / 3, i2 = tid % 3;
        wpostp[g][i2] = pack2h(w_post[g * 9 + i2 * 3], w_post[g * 9 + i2 * 3 + 1]);
        wpost2f[g][i2] = w_post[g * 9 + i2 * 3 + 2];
    }
    if (tid < 128) {
        int ff = tid >> 3, j = tid & 7;
        wposmp[ff][j] = pack2h(w_posm[ff * 16 + 2 * j], w_posm[ff * 16 + 2 * j + 1]);
    }
    for (int i = tid; i < 288; i += 256) {
        int g = i / 18, r = i % 18;
        int qp = q0 - 2 + r;
        if (qp >= 0) { mst[g][r] = mrow[g * S + qp]; rst[g][r] = rlrow[g * S + qp]; }
        else         { mst[g][r] = 0.f; rst[g][r] = 0.f; }
    }

    const int ql = tid >> 4, kb = (tid & 15) * 2;
    const int wv = tid >> 6, lane = tid & 63;
    const int lr = lane & 15, lk = lane >> 4;

    f32x4 acc[4][4];
#pragma unroll
    for (int a = 0; a < 4; ++a)
#pragma unroll
        for (int b = 0; b < 4; ++b) acc[a][b] = (f32x4){0.f, 0.f, 0.f, 0.f};

    __syncthreads();

    for (int k0 = kstart; k0 < kend; k0 += 32) {
        // stage normalized probs as f16: 16g x 18r x 17 uint-pairs
        for (int i = tid; i < 4896; i += 256) {
            int g = i / 306, rem = i % 306;
            int r = rem / 17, c2 = (rem % 17) * 2;
            int qp = q0 - 2 + r;
            int kp = k0 - 2 + c2;
            float p0 = 0.f, p1 = 0.f;
            if (qp >= 0 && kp >= 0) {
                unsigned int u = *(const unsigned int*)
                    &sc[((size_t)(g * (SQ + 16) + qp - (qs - 16))) * S + kp];
                float mm = mst[g][r], rr = rst[g][r];
                if (kp <= qp)     p0 = __expf(h2f((unsigned short)(u & 0xffff)) - mm) * rr;
                if (kp + 1 <= qp) p1 = __expf(h2f((unsigned short)(u >> 16)) - mm) * rr;
            }
            *(unsigned int*)&ps[g][r][c2] = pack2h(p0, p1);
        }
        __syncthreads();  // barA: ps ready; also protects pm2 (prev MFMA reads done)

        // 3x3 conv via dot2 (per pair of g, packed immediately) + dot2 mix
        {
            unsigned int cgp0[8], cgp1[8];
#pragma unroll
            for (int gp = 0; gp < 8; ++gp) {
                float cv[2][2];   // [g-in-pair][col]
#pragma unroll
                for (int g2 = 0; g2 < 2; ++g2) {
                    int g = gp * 2 + g2;
                    float c0 = 0.f, c1 = 0.f;
#pragma unroll
                    for (int i2 = 0; i2 < 3; ++i2) {
                        unsigned int u0 = *(const unsigned int*)&ps[g][ql + i2][kb];
                        unsigned int u1 = *(const unsigned int*)&ps[g][ql + i2][kb + 2];
                        unsigned int sh = (u0 >> 16) | (u1 << 16);
                        unsigned int wp = wpostp[g][i2];
                        float w2 = wpost2f[g][i2];
                        c0 = fdot2f(wp, u0, c0);
                        c1 = fdot2f(wp, sh, c1);
                        c0 += w2 * h2f((unsigned short)(u1 & 0xffff));
                        c1 += w2 * h2f((unsigned short)(u1 >> 16));
                    }
                    cv[g2][0] = c0; cv[g2][1] = c1;
                }
                cgp0[gp] = pack2h(cv[0][0], cv[1][0]);
                cgp1[gp] = pack2h(cv[0][1], cv[1][1]);
            }
            int q = q0 + ql, k = k0 + kb;
            bool val0 = (k <= q) && (k < kend);
            bool val1 = (k + 1 <= q) && (k + 1 < kend);
#pragma unroll
            for (int ff = 0; ff < 16; ++ff) {
                float s0 = 0.f, s1 = 0.f;
#pragma unroll
                for (int j = 0; j < 8; ++j) {
                    unsigned int w = wposmp[ff][j];
                    s0 = fdot2f(w, cgp0[j], s0);
                    s1 = fdot2f(w, cgp1[j], s1);
                }
                *(unsigned int*)&pm2[ff][ql][kb] = pack2h(val0 ? s0 : 0.f, val1 ? s1 : 0.f);
            }
        }
        __syncthreads();  // barB: pm2 ready

        // MFMA PV: wave wv handles heads wv*4..wv*4+3; B-frags direct from global vt
#pragma unroll
        for (int hh = 0; hh < 4; ++hh) {
            int f = wv * 4 + hh;
            f16x8 a = *(const f16x8*)&pm2[f][lr][lk * 8];
#pragma unroll
            for (int tc = 0; tc < 4; ++tc) {
                uint4 braw = *(const uint4*)
                    &vt[((size_t)(f * D + tc * 16 + lr)) * S + k0 + lk * 8];
                f16x8 b;
                __builtin_memcpy(&b, &braw, 16);
                acc[hh][tc] = __builtin_amdgcn_mfma_f32_16x16x32_f16(a, b, acc[hh][tc], 0, 0, 0);
            }
        }
        // next iteration's barA orders MFMA pm2-reads vs next conv writes
    }

    // epilogue: one atomicAdd pass
#pragma unroll
    for (int hh = 0; hh < 4; ++hh) {
        int f = wv * 4 + hh;
#pragma unroll
        for (int tc = 0; tc < 4; ++tc) {
#pragma unroll
            for (int i = 0; i < 4; ++i) {
                int q = q0 + lk * 4 + i;
                int d = tc * 16 + lr;
                atomicAdd(&out[((size_t)q * H + f) * D + d], acc[hh][tc][i]);
            }
        }
    }
}

// ===========================================================================
// Fallback path (round-2 kernels, verbatim): used when ws_size is too small.
// ===========================================================================
__global__ __launch_bounds__(256) void fb_stats_kernel(
        const float* __restrict__ xq, const float* __restrict__ xk,
        const float* __restrict__ w_pre, const float* __restrict__ w_psm,
        float* __restrict__ mpart, float* __restrict__ lpart) {
    const int kc = blockIdx.x, qt = blockIdx.y;
    const int q0 = qt * 16;
    const int kstart = kc * 256;
    if (kstart > q0 + 15) return;
    const int kend = min(kstart + 256, q0 + 16);
    const int tid = threadIdx.x;

    __shared__ unsigned short Qs[2][32][72];
    __shared__ unsigned short Ks[2][48][72];
    __shared__ float raws[32][50];
    __shared__ float wpre_s[16 * 66];
    __shared__ float wpsm_s[256];

    for (int i = tid; i < 16 * 66; i += 256) wpre_s[i] = w_pre[i];
    wpsm_s[tid] = w_psm[tid];

    const int ql = tid >> 4;
    const int kb = (tid & 15) * 2;
    const int q = q0 + ql;

    float mreg[16], lreg[16];
#pragma unroll
    for (int g = 0; g < 16; ++g) { mreg[g] = -INFINITY; lreg[g] = 0.f; }

    for (int k0 = kstart; k0 < kend; k0 += 32) {
        float acc0[16], acc1[16];
#pragma unroll
        for (int g = 0; g < 16; ++g) { acc0[g] = 0.f; acc1[g] = 0.f; }

        for (int h = 0; h < H; ++h) {
            {
                int r = tid >> 3, d = (tid & 7) * 8;
                int qp = q0 - 5 + r;
                float4 a = {0,0,0,0}, b = {0,0,0,0};
                if (r < 21 && qp >= 0) {
                    const float* p = &xq[(h * S + qp) * D + d];
                    a = *(const float4*)p; b = *(const float4*)(p + 4);
                }
                uint4 vh, vl; stage_hilo(a, b, &vh, &vl);
                *(uint4*)&Qs[0][r][d] = vh;
                *(uint4*)&Qs[1][r][d] = vl;
            }
            for (int i = tid; i < 384; i += 256) {
                int r = i >> 3, d = (i & 7) * 8;
                int kp = k0 - 10 + r;
                float4 a = {0,0,0,0}, b = {0,0,0,0};
                if (r < 42 && kp >= 0) {
                    const float* p = &xk[(h * S + kp) * D + d];
                    a = *(const float4*)p; b = *(const float4*)(p + 4);
                }
                uint4 vh, vl; stage_hilo(a, b, &vh, &vl);
                *(uint4*)&Ks[0][r][d] = vh;
                *(uint4*)&Ks[1][r][d] = vl;
            }
            __syncthreads();
            {
                int w = tid >> 6, l = tid & 63;
                int lr = l & 15, lk = l >> 4;
                for (int t = w; t < 6; t += 4) {
                    int tr = t / 3, tc = t % 3;
                    f32x4 acc = {0.f, 0.f, 0.f, 0.f};
#pragma unroll
                    for (int ks = 0; ks < 2; ++ks) {
                        int db = ks * 32 + lk * 8;
                        bf16x8 ah = *(const bf16x8*)&Qs[0][tr * 16 + lr][db];
                        bf16x8 al = *(const bf16x8*)&Qs[1][tr * 16 + lr][db];
                        bf16x8 bh = *(const bf16x8*)&Ks[0][tc * 16 + lr][db];
                        bf16x8 bl = *(const bf16x8*)&Ks[1][tc * 16 + lr][db];
                        acc = __builtin_amdgcn_mfma_f32_16x16x32_bf16(ah, bh, acc, 0, 0, 0);
                        acc = __builtin_amdgcn_mfma_f32_16x16x32_bf16(ah, bl, acc, 0, 0, 0);
                        acc = __builtin_amdgcn_mfma_f32_16x16x32_bf16(al, bh, acc, 0, 0, 0);
                    }
#pragma unroll
                    for (int i = 0; i < 4; ++i) {
                        int row = tr * 16 + lk * 4 + i;
                        int col = tc * 16 + lr;
                        int qp = q0 - 5 + row, kp = k0 - 10 + col;
                        raws[row][col] = (kp >= 0 && kp <= qp) ? acc[i] * SCALEQK : 0.f;
                    }
                }
            }
            __syncthreads();
            {
                float c0 = 0.f, c1 = 0.f;
#pragma unroll
                for (int i2 = 0; i2 < 6; ++i2) {
                    const float* rp = &raws[ql + i2][kb];
                    float v[12];
#pragma unroll
                    for (int j = 0; j < 6; ++j) {
                        float2 t = *(const float2*)(rp + 2 * j);
                        v[2 * j] = t.x; v[2 * j + 1] = t.y;
                    }
                    const float* wp = &wpre_s[h * 66 + i2 * 11];
#pragma unroll
                    for (int j = 0; j < 11; ++j) { c0 += wp[j] * v[j]; c1 += wp[j] * v[j + 1]; }
                }
#pragma unroll
                for (int g = 0; g < 16; ++g) {
                    float wg = wpsm_s[g * 16 + h];
                    acc0[g] += wg * c0; acc1[g] += wg * c1;
                }
            }
        }
        int kk = k0 + kb;
#pragma unroll
        for (int g = 0; g < 16; ++g) {
            if (kk <= q)     online_upd(mreg[g], lreg[g], acc0[g]);
            if (kk + 1 <= q) online_upd(mreg[g], lreg[g], acc1[g]);
        }
    }
#pragma unroll
    for (int g = 0; g < 16; ++g) {
        float m = mreg[g], l = lreg[g];
#pragma unroll
        for (int off = 1; off < 16; off <<= 1) {
            float m2 = __shfl_xor(m, off);
            float l2 = __shfl_xor(l, off);
            float nm = fmaxf(m, m2);
            float t1 = (l  > 0.f) ? l  * __expf(m  - nm) : 0.f;
            float t2 = (l2 > 0.f) ? l2 * __expf(m2 - nm) : 0.f;
            m = nm; l = t1 + t2;
        }
        if ((tid & 15) == 0) {
            mpart[((size_t)kc * H + g) * S + q] = m;
            lpart[((size_t)kc * H + g) * S + q] = l;
        }
    }
}

__global__ __launch_bounds__(256) void fb_reduce_kernel(
        const float* __restrict__ mpart, const float* __restrict__ lpart,
        float* __restrict__ mrow, float* __restrict__ rlrow) {
    int r = blockIdx.x * 256 + threadIdx.x;
    if (r >= H * S) return;
    int q = r & (S - 1);
    int nkc = (q >> 8) + 1;
    float m = -INFINITY;
    for (int kc = 0; kc < nkc; ++kc) m = fmaxf(m, mpart[(size_t)kc * H * S + r]);
    float l = 0.f;
    for (int kc = 0; kc < nkc; ++kc) {
        float li = lpart[(size_t)kc * H * S + r];
        float mi = mpart[(size_t)kc * H * S + r];
        if (li > 0.f) l += li * __expf(mi - m);
    }
    mrow[r] = m;
    rlrow[r] = 1.f / l;
}

__global__ __launch_bounds__(256) void fb_out_kernel(
        const float* __restrict__ xq, const float* __restrict__ xk,
        const float* __restrict__ xv,
        const float* __restrict__ w_pre, const float* __restrict__ w_psm,
        const float* __restrict__ w_post, const float* __restrict__ w_posm,
        const float* __restrict__ mrow, const float* __restrict__ rlrow,
        float* __restrict__ out) {
    const int qt = blockIdx.x, kc = blockIdx.y;
    const int q0 = qt * 8;
    const int kstart = kc * 256;
    if (kstart > q0 + 7) return;
    const int kend = min(kstart + 256, q0 + 8);
    const int tid = threadIdx.x;

    __shared__ unsigned short Qs[2][16][72];
    __shared__ unsigned short Ks[2][48][72];
    __shared__ float raws[16][50];
    __shared__ float ps[8][10][35];
    __shared__ float m2s[16][8][33];
    __shared__ float mst[16][10], rst[16][10];
    __shared__ float wpre_s[16 * 66], wpsm_s[256], wpost_s[144], wposm_s[256];

    for (int i = tid; i < 16 * 66; i += 256) wpre_s[i] = w_pre[i];
    wpsm_s[tid] = w_psm[tid];
    wposm_s[tid] = w_posm[tid];
    if (tid < 144) wpost_s[tid] = w_post[tid];
    for (int i = tid; i < 160; i += 256) {
        int g = i / 10, r = i % 10;
        int qp = q0 - 2 + r;
        if (qp >= 0) { mst[g][r] = mrow[g * S + qp]; rst[g][r] = rlrow[g * S + qp]; }
        else         { mst[g][r] = 0.f; rst[g][r] = 0.f; }
    }

    const int f = tid >> 4, qloc = (tid >> 1) & 7, dh = tid & 1;
    const int cr = tid / 17, cc = (tid % 17) * 2;
    const bool cvalid = tid < 170;
    const int ql2 = tid >> 5, kl = tid & 31;

    float oacc[32];
#pragma unroll
    for (int i = 0; i < 32; ++i) oacc[i] = 0.f;

    for (int k0 = kstart; k0 < kend; k0 += 32) {
        float a0[16], a1[16];
#pragma unroll
        for (int g = 0; g < 16; ++g) { a0[g] = 0.f; a1[g] = 0.f; }

        for (int h = 0; h < H; ++h) {
            if (tid < 128) {
                int r = tid >> 3, d = (tid & 7) * 8;
                int qp = q0 - 7 + r;
                float4 a = {0,0,0,0}, b = {0,0,0,0};
                if (qp >= 0 && qp < S) {
                    const float* p = &xq[(h * S + qp) * D + d];
                    a = *(const float4*)p; b = *(const float4*)(p + 4);
                }
                uint4 vh, vl; stage_hilo(a, b, &vh, &vl);
                *(uint4*)&Qs[0][r][d] = vh;
                *(uint4*)&Qs[1][r][d] = vl;
            }
            for (int i = tid; i < 384; i += 256) {
                int r = i >> 3, d = (i & 7) * 8;
                int kp = k0 - 12 + r;
                float4 a = {0,0,0,0}, b = {0,0,0,0};
                if (kp >= 0 && kp < S) {
                    const float* p = &xk[(h * S + kp) * D + d];
                    a = *(const float4*)p; b = *(const float4*)(p + 4);
                }
                uint4 vh, vl; stage_hilo(a, b, &vh, &vl);
                *(uint4*)&Ks[0][r][d] = vh;
                *(uint4*)&Ks[1][r][d] = vl;
            }
            __syncthreads();
            {
                int w = tid >> 6, l = tid & 63;
                int lr = l & 15, lk = l >> 4;
                if (w < 3) {
                    int tc = w;
                    f32x4 acc = {0.f, 0.f, 0.f, 0.f};
#pragma unroll
                    for (int ks = 0; ks < 2; ++ks) {
                        int db = ks * 32 + lk * 8;
                        bf16x8 ah = *(const bf16x8*)&Qs[0][lr][db];
                        bf16x8 al = *(const bf16x8*)&Qs[1][lr][db];
                        bf16x8 bh = *(const bf16x8*)&Ks[0][tc * 16 + lr][db];
                        bf16x8 bl = *(const bf16x8*)&Ks[1][tc * 16 + lr][db];
                        acc = __builtin_amdgcn_mfma_f32_16x16x32_bf16(ah, bh, acc, 0, 0, 0);
                        acc = __builtin_amdgcn_mfma_f32_16x16x32_bf16(ah, bl, acc, 0, 0, 0);
                        acc = __builtin_amdgcn_mfma_f32_16x16x32_bf16(al, bh, acc, 0, 0, 0);
                    }
#pragma unroll
                    for (int i = 0; i < 4; ++i) {
                        int row = lk * 4 + i, col = tc * 16 + lr;
                        int qp = q0 - 7 + row, kp = k0 - 12 + col;
                        raws[row][col] = (kp >= 0 && kp <= qp) ? acc[i] * SCALEQK : 0.f;
                    }
                }
            }
            __syncthreads();
            if (cvalid) {
                float c0 = 0.f, c1 = 0.f;
#pragma unroll
                for (int i2 = 0; i2 < 6; ++i2) {
                    const float* rp = &raws[cr + i2][cc];
                    float v[12];
#pragma unroll
                    for (int j = 0; j < 6; ++j) {
                        float2 t = *(const float2*)(rp + 2 * j);
                        v[2 * j] = t.x; v[2 * j + 1] = t.y;
                    }
                    const float* wp = &wpre_s[h * 66 + i2 * 11];
#pragma unroll
                    for (int j = 0; j < 11; ++j) { c0 += wp[j] * v[j]; c1 += wp[j] * v[j + 1]; }
                }
#pragma unroll
                for (int g = 0; g < 16; ++g) {
                    float wg = wpsm_s[g * 16 + h];
                    a0[g] += wg * c0; a1[g] += wg * c1;
                }
            }
        }

        float m2f[16];
#pragma unroll
        for (int i = 0; i < 16; ++i) m2f[i] = 0.f;

        for (int half = 0; half < 2; ++half) {
            if (cvalid) {
                int qp = q0 - 2 + cr;
                int kp0 = k0 - 2 + cc, kp1 = kp0 + 1;
#pragma unroll
                for (int g8 = 0; g8 < 8; ++g8) {
                    int g = half * 8 + g8;
                    float p0 = 0.f, p1 = 0.f;
                    if (qp >= 0) {
                        float mm = mst[g][cr], rr = rst[g][cr];
                        if (kp0 >= 0 && kp0 <= qp) p0 = __expf(a0[g] - mm) * rr;
                        if (kp1 >= 0 && kp1 <= qp) p1 = __expf(a1[g] - mm) * rr;
                    }
                    ps[g8][cr][cc] = p0;
                    ps[g8][cr][cc + 1] = p1;
                }
            }
            __syncthreads();
            {
                float cg[8];
#pragma unroll
                for (int g8 = 0; g8 < 8; ++g8) {
                    float c = 0.f;
#pragma unroll
                    for (int i2 = 0; i2 < 3; ++i2)
#pragma unroll
                        for (int j2 = 0; j2 < 3; ++j2)
                            c += wpost_s[(half * 8 + g8) * 9 + i2 * 3 + j2] * ps[g8][ql2 + i2][kl + j2];
                    cg[g8] = c;
                }
#pragma unroll
                for (int ff = 0; ff < 16; ++ff) {
                    float s = 0.f;
#pragma unroll
                    for (int g8 = 0; g8 < 8; ++g8) s += wposm_s[ff * 16 + half * 8 + g8] * cg[g8];
                    m2f[ff] += s;
                }
            }
            if (half == 0) __syncthreads();
        }
        {
            int q = q0 + ql2, k = k0 + kl;
            bool valid = (k <= q) && (k < kend);
#pragma unroll
            for (int ff = 0; ff < 16; ++ff) m2s[ff][ql2][kl] = valid ? m2f[ff] : 0.f;
        }
        __syncthreads();
        for (int kl2 = 0; kl2 < 32; ++kl2) {
            int k = k0 + kl2;
            if (k >= kend) break;
            float s = m2s[f][qloc][kl2];
            if (s != 0.f) {
                const float* vp = &xv[(f * S + k) * D + dh * 32];
#pragma unroll
                for (int d4 = 0; d4 < 8; ++d4) {
                    float4 v = *(const float4*)(vp + d4 * 4);
                    oacc[d4 * 4 + 0] += s * v.x;
                    oacc[d4 * 4 + 1] += s * v.y;
                    oacc[d4 * 4 + 2] += s * v.z;
                    oacc[d4 * 4 + 3] += s * v.w;
                }
            }
        }
        __syncthreads();
    }

    int q = q0 + qloc;
    float* op = out + ((size_t)q * H + f) * D + dh * 32;
#pragma unroll
    for (int i = 0; i < 32; ++i) atomicAdd(op + i, oacc[i]);
}

// ===========================================================================
extern "C" void kernel_launch(void* const* d_in, const int* in_sizes, int n_in,
                              void* d_out, int out_size, void* d_ws, size_t ws_size,
                              hipStream_t stream) {
    const float* xq     = (const float*)d_in[0];
    const float* xk     = (const float*)d_in[1];
    const float* xv     = (const float*)d_in[2];
    const float* w_pre  = (const float*)d_in[4];
    const float* w_post = (const float*)d_in[5];
    const float* w_psm  = (const float*)d_in[6];
    const float* w_posm = (const float*)d_in[7];
    float* out = (float*)d_out;

    hipMemsetAsync(d_out, 0, sizeof(float) * (size_t)out_size, stream);

    const size_t qkb   = (size_t)H * S * D * 2;   // 4 MiB per hi/lo array
    const size_t vtb   = (size_t)H * D * S * 2;   // 4 MiB
    const size_t statb = (size_t)H * S * 4;       // 128 KiB
    const size_t base  = 4 * qkb + vtb + 2 * statb;

    int SQ = 0;
    const int cands[5] = {2048, 1024, 512, 256, 128};
    for (int c = 0; c < 5; ++c) {
        size_t rb  = (size_t)H * (cands[c] + 64) * S * 2;
        size_t scb = (size_t)H * (cands[c] + 16) * S * 2 + 128;
        if (base + rb + scb <= ws_size) { SQ = cands[c]; break; }
    }

    if (SQ == 0) {
        float* mpart = (float*)d_ws;
        float* lpart = mpart + (size_t)8 * H * S;
        float* mrow  = lpart + (size_t)8 * H * S;
        float* rlrow = mrow + (size_t)H * S;
        dim3 g1(8, 128);
        fb_stats_kernel<<<g1, 256, 0, stream>>>(xq, xk, w_pre, w_psm, mpart, lpart);
        fb_reduce_kernel<<<128, 256, 0, stream>>>(mpart, lpart, mrow, rlrow);
        dim3 g2(256, 8);
        fb_out_kernel<<<g2, 256, 0, stream>>>(xq, xk, xv, w_pre, w_psm, w_post, w_posm,
                                              mrow, rlrow, out);
        return;
    }

    char* p = (char*)d_ws;
    unsigned short* qhi = (unsigned short*)p;            p += qkb;
    unsigned short* qlo = (unsigned short*)p;            p += qkb;
    unsigned short* khi = (unsigned short*)p;            p += qkb;
    unsigned short* klo = (unsigned short*)p;            p += qkb;
    unsigned short* vt  = (unsigned short*)p;            p += vtb;
    float* mrow  = (float*)p;                            p += statb;
    float* rlrow = (float*)p;                            p += statb;
    unsigned short* Rbuf = (unsigned short*)p;           p += (size_t)H * (SQ + 64) * S * 2;
    unsigned short* sc   = (unsigned short*)p;

    const int n8 = H * S * D / 8;
    mta_cvt_kernel<<<512, 256, 0, stream>>>(xq, qhi, qlo, SCALEQK, n8);
    mta_cvt_kernel<<<512, 256, 0, stream>>>(xk, khi, klo, 1.0f, n8);
    dim3 gv(S / 64, H);
    mta_vt_kernel<<<gv, 256, 0, stream>>>(xv, vt);

    for (int qs = 0; qs < S; qs += SQ) {
        dim3 gg(S / 64, SQ / 64 + 1, H);
        mta_gemm_kernel<<<gg, 256, 0, stream>>>(qhi, qlo, khi, klo, Rbuf, qs, SQ);
        dim3 gc(S / 64, SQ / 16 + 1);
        mta_convmix_kernel<<<gc, 256, 0, stream>>>(Rbuf, w_pre, w_psm, sc, qs, SQ);
        mta_rowstats_kernel<<<4 * SQ, 256, 0, stream>>>(sc, mrow, rlrow, qs, SQ);
        dim3 g2(SQ / 16, S / CH);
        mta_out2_kernel<<<g2, 256, 0, stream>>>(sc, mrow, rlrow, vt, w_post, w_posm,
                                                out, qs, SQ);
    }
}

// Round 17
// 478.997 us; speedup vs baseline: 1.0893x; 1.0893x over previous
//
#include <hip/hip_runtime.h>
#include <math.h>

#define H 16
#define S 2048
#define D 64
#define SCALEQK 0.125f
#define CH 256

typedef __attribute__((ext_vector_type(4))) float f32x4;
typedef __attribute__((ext_vector_type(8))) short bf16x8;
typedef __attribute__((ext_vector_type(8))) _Float16 f16x8;
typedef __attribute__((ext_vector_type(4))) _Float16 f16x4;
typedef __attribute__((ext_vector_type(2))) _Float16 f16x2;

__device__ inline float h2f(unsigned short b) {
    _Float16 h; __builtin_memcpy(&h, &b, 2); return (float)h;
}
__device__ inline unsigned short f2h(float x) {
    _Float16 h = (_Float16)x; unsigned short b; __builtin_memcpy(&b, &h, 2); return b;
}
__device__ inline unsigned int pack2h(float a, float b) {
    return (unsigned int)f2h(a) | ((unsigned int)f2h(b) << 16);
}

// dot2: c += a.lo*b.lo + a.hi*b.hi with f16 operands, f32 accumulate
__device__ inline float fdot2f(unsigned int a, unsigned int b, float c) {
#if __has_builtin(__builtin_amdgcn_fdot2)
    f16x2 av, bv;
    __builtin_memcpy(&av, &a, 4);
    __builtin_memcpy(&bv, &b, 4);
    return __builtin_amdgcn_fdot2(av, bv, c, false);
#else
    return c + h2f((unsigned short)(a & 0xffff)) * h2f((unsigned short)(b & 0xffff))
             + h2f((unsigned short)(a >> 16))    * h2f((unsigned short)(b >> 16));
#endif
}

// split f32 -> bf16 hi + bf16 lo (residual), rne; packed into two uint4 (8 elems)
__device__ inline void stage_hilo(float4 a, float4 b, uint4* vh, uint4* vl) {
    float xs[8] = {a.x, a.y, a.z, a.w, b.x, b.y, b.z, b.w};
    unsigned int hh[8], ll[8];
#pragma unroll
    for (int j = 0; j < 8; ++j) {
        unsigned int u = __float_as_uint(xs[j]);
        unsigned int h = (u + 0x7fffu + ((u >> 16) & 1u)) >> 16;
        float r = xs[j] - __uint_as_float(h << 16);
        unsigned int u2 = __float_as_uint(r);
        hh[j] = h;
        ll[j] = (u2 + 0x7fffu + ((u2 >> 16) & 1u)) >> 16;
    }
    uint4 h4, l4;
    h4.x = hh[0] | (hh[1] << 16); h4.y = hh[2] | (hh[3] << 16);
    h4.z = hh[4] | (hh[5] << 16); h4.w = hh[6] | (hh[7] << 16);
    l4.x = ll[0] | (ll[1] << 16); l4.y = ll[2] | (ll[3] << 16);
    l4.z = ll[4] | (ll[5] << 16); l4.w = ll[6] | (ll[7] << 16);
    *vh = h4; *vl = l4;
}

__device__ inline void online_upd(float& m, float& l, float x) {
    if (x > m) { l = l * __expf(m - x) + 1.f; m = x; }
    else       { l += __expf(x - m); }
}

// ---------------------------------------------------------------------------
// K_cvt: f32 src -> (hi, lo) bf16 split arrays, optional scale. 8 elems/thread.
__global__ __launch_bounds__(256) void mta_cvt_kernel(const float* __restrict__ src,
                                                      unsigned short* __restrict__ hi,
                                                      unsigned short* __restrict__ lo,
                                                      float scale, int n8) {
    int i = blockIdx.x * 256 + threadIdx.x;
    int stride = gridDim.x * 256;
    for (; i < n8; i += stride) {
        const float* p = src + (size_t)i * 8;
        float4 a = *(const float4*)p;
        float4 b = *(const float4*)(p + 4);
        a.x *= scale; a.y *= scale; a.z *= scale; a.w *= scale;
        b.x *= scale; b.y *= scale; b.z *= scale; b.w *= scale;
        uint4 vh, vl; stage_hilo(a, b, &vh, &vl);
        *(uint4*)&hi[(size_t)i * 8] = vh;
        *(uint4*)&lo[(size_t)i * 8] = vl;
    }
}

// K_vt: xv[f][k][d] f32 -> vt[f][d][k] f16, 64x64 LDS-tiled transpose.
__global__ __launch_bounds__(256) void mta_vt_kernel(const float* __restrict__ xv,
                                                     unsigned short* __restrict__ vt) {
    const int kt = blockIdx.x, f = blockIdx.y;
    const int tid = threadIdx.x;
    __shared__ unsigned short lt[64][65];
#pragma unroll
    for (int i = 0; i < 16; ++i) {
        int idx = tid + i * 256;
        int r = idx >> 6, c = idx & 63;
        lt[r][c] = f2h(xv[((size_t)f * S + kt * 64 + r) * D + c]);
    }
    __syncthreads();
#pragma unroll
    for (int i = 0; i < 16; ++i) {
        int idx = tid + i * 256;
        int d = idx >> 6, k = idx & 63;
        vt[((size_t)f * D + d) * S + kt * 64 + k] = lt[k][d];
    }
}

// ---------------------------------------------------------------------------
// K_gemm: raw scores per head, 64q x 64k tile, split-bf16 (hi*hi+hi*lo+lo*hi),
// causal-zeroed, written f16 to R[h][lrow][k]. lrow 0 == global row qs-64.
__global__ __launch_bounds__(256) void mta_gemm_kernel(
        const unsigned short* __restrict__ qhi, const unsigned short* __restrict__ qlo,
        const unsigned short* __restrict__ khi, const unsigned short* __restrict__ klo,
        unsigned short* __restrict__ R, int qs, int SQ) {
    const int kt = blockIdx.x, qt = blockIdx.y, h = blockIdx.z;
    const int q0 = qs - 64 + qt * 64;
    const int k0 = kt * 64;
    if (k0 > q0 + 68) return;
    const int tid = threadIdx.x;
    const int SQ64 = SQ + 64;

    __shared__ unsigned short Qs[2][64][72];   // [hi/lo][row][col]
    __shared__ unsigned short Ks[2][64][72];
    __shared__ unsigned short Ro[64][72];

    {   // stage: each thread 16 cols of one row for Q and K (hi+lo)
        int r = tid >> 2, d = (tid & 3) * 16;
        int gq = q0 + r;
        uint4 z = {0u, 0u, 0u, 0u};
        uint4 a0 = z, a1 = z, b0 = z, b1 = z;
        if (gq >= 0) {
            size_t off = ((size_t)h * S + gq) * D + d;
            a0 = *(const uint4*)&qhi[off]; a1 = *(const uint4*)&qhi[off + 8];
            b0 = *(const uint4*)&qlo[off]; b1 = *(const uint4*)&qlo[off + 8];
        }
        *(uint4*)&Qs[0][r][d] = a0; *(uint4*)&Qs[0][r][d + 8] = a1;
        *(uint4*)&Qs[1][r][d] = b0; *(uint4*)&Qs[1][r][d + 8] = b1;
        size_t offk = ((size_t)h * S + (k0 + r)) * D + d;
        uint4 c0 = *(const uint4*)&khi[offk];
        uint4 c1 = *(const uint4*)&khi[offk + 8];
        uint4 d0 = *(const uint4*)&klo[offk];
        uint4 d1 = *(const uint4*)&klo[offk + 8];
        *(uint4*)&Ks[0][r][d] = c0; *(uint4*)&Ks[0][r][d + 8] = c1;
        *(uint4*)&Ks[1][r][d] = d0; *(uint4*)&Ks[1][r][d + 8] = d1;
    }
    __syncthreads();

    const int w = tid >> 6, lane = tid & 63;
    const int wr = w >> 1, wc = w & 1;
    const int lr = lane & 15, lk = lane >> 4;

    f32x4 acc[2][2];
#pragma unroll
    for (int mi = 0; mi < 2; ++mi)
#pragma unroll
        for (int ni = 0; ni < 2; ++ni) acc[mi][ni] = (f32x4){0.f, 0.f, 0.f, 0.f};

#pragma unroll
    for (int ks = 0; ks < 2; ++ks) {
        int db = ks * 32 + lk * 8;
#pragma unroll
        for (int mi = 0; mi < 2; ++mi) {
            bf16x8 ah = *(const bf16x8*)&Qs[0][wr * 32 + mi * 16 + lr][db];
            bf16x8 al = *(const bf16x8*)&Qs[1][wr * 32 + mi * 16 + lr][db];
#pragma unroll
            for (int ni = 0; ni < 2; ++ni) {
                bf16x8 bh = *(const bf16x8*)&Ks[0][wc * 32 + ni * 16 + lr][db];
                bf16x8 bl = *(const bf16x8*)&Ks[1][wc * 32 + ni * 16 + lr][db];
                acc[mi][ni] = __builtin_amdgcn_mfma_f32_16x16x32_bf16(ah, bh, acc[mi][ni], 0, 0, 0);
                acc[mi][ni] = __builtin_amdgcn_mfma_f32_16x16x32_bf16(ah, bl, acc[mi][ni], 0, 0, 0);
                acc[mi][ni] = __builtin_amdgcn_mfma_f32_16x16x32_bf16(al, bh, acc[mi][ni], 0, 0, 0);
            }
        }
    }

    // causal-zero + pack to Ro (f16)
#pragma unroll
    for (int mi = 0; mi < 2; ++mi)
#pragma unroll
        for (int ni = 0; ni < 2; ++ni)
#pragma unroll
            for (int i = 0; i < 4; ++i) {
                int row = wr * 32 + mi * 16 + lk * 4 + i;
                int col = wc * 32 + ni * 16 + lr;
                int gq = q0 + row, gk = k0 + col;
                Ro[row][col] = f2h((gk <= gq) ? acc[mi][ni][i] : 0.f);
            }
    __syncthreads();

    // coalesced global write: 64 rows x 128B
#pragma unroll
    for (int ii = 0; ii < 2; ++ii) {
        int idx = tid + ii * 256;
        int row = idx >> 3, c8 = (idx & 7) * 8;
        int lrow = qt * 64 + row;
        *(uint4*)&R[((size_t)h * SQ64 + lrow) * S + k0 + c8] = *(const uint4*)&Ro[row][c8];
    }
}

// ---------------------------------------------------------------------------
// K_convmix v5: f16 raw staging (no cvt), conv via v_dot2_f32_f16,
// 2-head phases (8 barriers), MFMA head-mix epilogue. 16q x 64k tile.
__global__ __launch_bounds__(256) void mta_convmix_kernel(
        const unsigned short* __restrict__ R,
        const float* __restrict__ w_pre, const float* __restrict__ w_psm,
        unsigned short* __restrict__ sc, int qs, int SQ) {
    const int kc = blockIdx.x, qt = blockIdx.y;
    const int q0 = qs - 16 + qt * 16;   // qt==0 is the stripe halo tile
    const int k0 = kc * 64;
    if (k0 > q0 + 15) return;
    const int tid = threadIdx.x;
    const int SQ64 = SQ + 64;

    // f16 cols 0..79 map to global cols k0-16 .. k0+63; row padded to 88 f16
    __shared__ unsigned short raw_u16[2][2][21][88];   // [buf][tile-in-phase][row][col]
    __shared__ unsigned short co[1024][16];            // [pixel][h^(x<<2)]
    __shared__ unsigned int wpk[16][6][6];             // f16-pair packed conv weights
    __shared__ unsigned short wpsmf[16][16];           // f16 W[g][h]

    for (int idx = tid; idx < 576; idx += 256) {
        int h = idx / 36, i2 = (idx % 36) / 6, ip = idx % 6;
        float w0 = w_pre[h * 66 + i2 * 11 + ip * 2];
        float w1 = (ip < 5) ? w_pre[h * 66 + i2 * 11 + ip * 2 + 1] : 0.f;
        wpk[h][i2][ip] = pack2h(w0, w1);
    }
    wpsmf[tid >> 4][tid & 15] = f2h(w_psm[tid]);

    const int ql = tid & 15;            // output row
    const int kb = (tid >> 4) * 4;      // output col group (4 cols)

    // staging map: 210 uint4 loads (21 rows x 10 chunks of 8 f16)
    const int sr = tid / 10, sc8 = tid % 10;
    const bool sact = (tid < 210);
    const bool sval = sact && (k0 + sc8 * 8 >= 16);     // global col >= 0
    const size_t srow_off = (size_t)(qt * 16 + sr + 43) * S + (k0 - 16 + sc8 * 8);

    uint4 sA = {0u, 0u, 0u, 0u}, sB = {0u, 0u, 0u, 0u};

#define LOADC(hh, dst) do { \
        if (sval) dst = *(const uint4*)&R[(size_t)(hh) * SQ64 * S + srow_off]; \
        else { dst.x = 0u; dst.y = 0u; dst.z = 0u; dst.w = 0u; } \
    } while (0)

#define WRITEC(bb, tt, src) do { if (sact) { \
        *(uint4*)&raw_u16[bb][tt][sr][sc8 * 8] = src; } \
    } while (0)

#define CONVC(hh, bb, tt) do { \
        float c0_ = 0.f, c1_ = 0.f, c2_ = 0.f, c3_ = 0.f; \
        _Pragma("unroll") \
        for (int i2_ = 0; i2_ < 6; ++i2_) { \
            const unsigned int* rp_ = \
                (const unsigned int*)&raw_u16[bb][tt][ql + i2_][0] + (kb / 2 + 3); \
            unsigned int P_[7]; \
            _Pragma("unroll") \
            for (int i_ = 0; i_ < 7; ++i_) P_[i_] = rp_[i_]; \
            unsigned int Sv_[6]; \
            _Pragma("unroll") \
            for (int i_ = 0; i_ < 6; ++i_) Sv_[i_] = (P_[i_] >> 16) | (P_[i_ + 1] << 16); \
            unsigned int T_ = P_[6] >> 16; \
            const unsigned int* wp_ = &wpk[hh][i2_][0]; \
            _Pragma("unroll") \
            for (int i_ = 0; i_ < 6; ++i_) { \
                unsigned int w_ = wp_[i_]; \
                c0_ = fdot2f(w_, P_[i_], c0_); \
                c1_ = fdot2f(w_, Sv_[i_], c1_); \
                c2_ = fdot2f(w_, P_[i_ + 1], c2_); \
                c3_ = fdot2f(w_, (i_ < 5) ? Sv_[i_ + 1] : T_, c3_); \
            } \
        } \
        { float cc_[4] = {c0_, c1_, c2_, c3_}; \
          int p0_ = ql * 64 + kb; \
          _Pragma("unroll") \
          for (int j_ = 0; j_ < 4; ++j_) { \
              int pp_ = p0_ + j_; \
              int x_ = ((pp_ >> 2) ^ (pp_ >> 6)) & 3; \
              co[pp_][(hh) ^ (x_ << 2)] = f2h(cc_[j_]); } } \
    } while (0)

    LOADC(0, sA);
    LOADC(1, sB);
    WRITEC(0, 0, sA);
    WRITEC(0, 1, sB);
    __syncthreads();
    for (int ph = 0; ph < 8; ++ph) {
        int bb = ph & 1;
        if (ph < 7) { LOADC(2 * ph + 2, sA); LOADC(2 * ph + 3, sB); }
        CONVC(2 * ph,     bb, 0);
        CONVC(2 * ph + 1, bb, 1);
        if (ph < 7) { WRITEC(bb ^ 1, 0, sA); WRITEC(bb ^ 1, 1, sB); }
        __syncthreads();        // last iteration: co complete before mix
    }
#undef LOADC
#undef WRITEC
#undef CONVC

    // head-mix: out[g][p] = sum_h W[g][h] * co[p][h], one MFMA per 16-pixel tile
    const int lane = tid & 63, wv = tid >> 6;
    const int hg = lane >> 4;
#if __has_builtin(__builtin_amdgcn_mfma_f32_16x16x16f16)
    f16x4 afrag = *(const f16x4*)&wpsmf[lane & 15][hg * 4];
    for (int t = wv; t < 64; t += 4) {
        int p = t * 16 + (lane & 15);
        int x = ((p >> 2) ^ (p >> 6)) & 3;
        f16x4 bfrag = *(const f16x4*)&co[p][(hg ^ x) << 2];
        f32x4 d = {0.f, 0.f, 0.f, 0.f};
        d = __builtin_amdgcn_mfma_f32_16x16x16f16(afrag, bfrag, d, 0, 0, 0);
        int qq = q0 + (p >> 6);
        int kk = k0 + (p & 63);
        int srow = qt * 16 + (p >> 6);
#pragma unroll
        for (int i = 0; i < 4; ++i) {
            int g = hg * 4 + i;
            sc[((size_t)(g * (SQ + 16) + srow)) * S + kk] =
                f2h((kk <= qq) ? d[i] : 0.f);
        }
    }
#else
    // VALU fallback (correctness path)
    for (int t = wv; t < 64; t += 4) {
        int p = t * 16 + (lane & 15);
        int x = ((p >> 2) ^ (p >> 6)) & 3;
        float ch[16];
#pragma unroll
        for (int a = 0; a < 4; ++a) {
            f16x4 b4 = *(const f16x4*)&co[p][(a ^ x) << 2];
#pragma unroll
            for (int tt = 0; tt < 4; ++tt) ch[a * 4 + tt] = (float)b4[tt];
        }
        int qq = q0 + (p >> 6);
        int kk = k0 + (p & 63);
        int srow = qt * 16 + (p >> 6);
#pragma unroll
        for (int i = 0; i < 4; ++i) {
            int g = hg * 4 + i;
            float s = 0.f;
#pragma unroll
            for (int hh = 0; hh < 16; ++hh) s += h2f(wpsmf[g][hh]) * ch[hh];
            sc[((size_t)(g * (SQ + 16) + srow)) * S + kk] =
                f2h((kk <= qq) ? s : 0.f);
        }
    }
#endif
}

// ---------------------------------------------------------------------------
// Stats: per (g,q) row of the stripe, m = max, l = sum exp(x-m) over k<=q.
__global__ __launch_bounds__(256) void mta_rowstats_kernel(
        const unsigned short* __restrict__ sc,
        float* __restrict__ mrow, float* __restrict__ rlrow, int qs, int SQ) {
    int row = blockIdx.x * 4 + (threadIdx.x >> 6);
    int lane = threadIdx.x & 63;
    int g = row / SQ, qq = row % SQ;
    int q = qs + qq;
    const unsigned short* rp = sc + ((size_t)(g * (SQ + 16) + qq + 16)) * S;

    float v[32];
#pragma unroll
    for (int it = 0; it < 4; ++it) {
        int kbase = it * 512 + lane * 8;
        if (it * 512 <= q) {
            uint4 u = *(const uint4*)&rp[kbase];
            unsigned int ws[4] = {u.x, u.y, u.z, u.w};
#pragma unroll
            for (int j = 0; j < 4; ++j) {
                float x0 = h2f((unsigned short)(ws[j] & 0xffff));
                float x1 = h2f((unsigned short)(ws[j] >> 16));
                v[it * 8 + 2 * j]     = (kbase + 2 * j     <= q) ? x0 : -INFINITY;
                v[it * 8 + 2 * j + 1] = (kbase + 2 * j + 1 <= q) ? x1 : -INFINITY;
            }
        } else {
#pragma unroll
            for (int j = 0; j < 8; ++j) v[it * 8 + j] = -INFINITY;
        }
    }
    float m = -INFINITY;
#pragma unroll
    for (int j = 0; j < 32; ++j) m = fmaxf(m, v[j]);
#pragma unroll
    for (int off = 1; off < 64; off <<= 1) m = fmaxf(m, __shfl_xor(m, off));
    float l = 0.f;
#pragma unroll
    for (int j = 0; j < 32; ++j) l += __expf(v[j] - m);
#pragma unroll
    for (int off = 1; off < 64; off <<= 1) l += __shfl_xor(l, off);
    if (lane == 0) { mrow[g * S + q] = m; rlrow[g * S + q] = 1.f / l; }
}

// ---------------------------------------------------------------------------
// Pass 2 (r12 version): probs = exp(sc-m)/l, 3x3 conv via dot2,
// w_posm mix via dot2 on packed f16 pairs, MFMA PV. 2 barriers per k-step.
__global__ __launch_bounds__(256) void mta_out2_kernel(
        const unsigned short* __restrict__ sc,
        const float* __restrict__ mrow, const float* __restrict__ rlrow,
        const unsigned short* __restrict__ vt,
        const float* __restrict__ w_post, const float* __restrict__ w_posm,
        float* __restrict__ out, int qs, int SQ) {
    const int qt = blockIdx.x, kc = blockIdx.y;
    const int q0 = qs + qt * 16;
    const int kstart = kc * CH;
    if (kstart > q0 + 15) return;
    const int kend = min(kstart + CH, q0 + 16);
    const int tid = threadIdx.x;

    __shared__ unsigned short ps[16][18][36];
    __shared__ unsigned short pm2[16][16][40];
    __shared__ float mst[16][18], rst[16][18];
    __shared__ unsigned int wpostp[16][3];   // f16 pair (w0,w1) per conv row
    __shared__ float wpost2f[16][3];         // w2 per conv row (f32)
    __shared__ unsigned int wposmp[16][8];   // w_posm f16 pairs over g

    if (tid < 48) {
        int g = tid / 3, i2 = tid % 3;
        wpostp[g][i2] = pack2h(w_post[g * 9 + i2 * 3], w_post[g * 9 + i2 * 3 + 1]);
        wpost2f[g][i2] = w_post[g * 9 + i2 * 3 + 2];
    }
    if (tid < 128) {
        int ff = tid >> 3, j = tid & 7;
        wposmp[ff][j] = pack2h(w_posm[ff * 16 + 2 * j], w_posm[ff * 16 + 2 * j + 1]);
    }
    for (int i = tid; i < 288; i += 256) {
        int g = i / 18, r = i % 18;
        int qp = q0 - 2 + r;
        if (qp >= 0) { mst[g][r] = mrow[g * S + qp]; rst[g][r] = rlrow[g * S + qp]; }
        else         { mst[g][r] = 0.f; rst[g][r] = 0.f; }
    }

    const int ql = tid >> 4, kb = (tid & 15) * 2;
    const int wv = tid >> 6, lane = tid & 63;
    const int lr = lane & 15, lk = lane >> 4;

    f32x4 acc[4][4];
#pragma unroll
    for (int a = 0; a < 4; ++a)
#pragma unroll
        for (int b = 0; b < 4; ++b) acc[a][b] = (f32x4){0.f, 0.f, 0.f, 0.f};

    __syncthreads();

    for (int k0 = kstart; k0 < kend; k0 += 32) {
        // stage normalized probs as f16: 16g x 18r x 17 uint-pairs
        for (int i = tid; i < 4896; i += 256) {
            int g = i / 306, rem = i % 306;
            int r = rem / 17, c2 = (rem % 17) * 2;
            int qp = q0 - 2 + r;
            int kp = k0 - 2 + c2;
            float p0 = 0.f, p1 = 0.f;
            if (qp >= 0 && kp >= 0) {
                unsigned int u = *(const unsigned int*)
                    &sc[((size_t)(g * (SQ + 16) + qp - (qs - 16))) * S + kp];
                float mm = mst[g][r], rr = rst[g][r];
                if (kp <= qp)     p0 = __expf(h2f((unsigned short)(u & 0xffff)) - mm) * rr;
                if (kp + 1 <= qp) p1 = __expf(h2f((unsigned short)(u >> 16)) - mm) * rr;
            }
            *(unsigned int*)&ps[g][r][c2] = pack2h(p0, p1);
        }
        __syncthreads();  // barA: ps ready; also protects pm2 (prev MFMA reads done)

        // 3x3 conv via dot2 (per pair of g, packed immediately) + dot2 mix
        {
            unsigned int cgp0[8], cgp1[8];
#pragma unroll
            for (int gp = 0; gp < 8; ++gp) {
                float cv[2][2];   // [g-in-pair][col]
#pragma unroll
                for (int g2 = 0; g2 < 2; ++g2) {
                    int g = gp * 2 + g2;
                    float c0 = 0.f, c1 = 0.f;
#pragma unroll
                    for (int i2 = 0; i2 < 3; ++i2) {
                        unsigned int u0 = *(const unsigned int*)&ps[g][ql + i2][kb];
                        unsigned int u1 = *(const unsigned int*)&ps[g][ql + i2][kb + 2];
                        unsigned int sh = (u0 >> 16) | (u1 << 16);
                        unsigned int wp = wpostp[g][i2];
                        float w2 = wpost2f[g][i2];
                        c0 = fdot2f(wp, u0, c0);
                        c1 = fdot2f(wp, sh, c1);
                        c0 += w2 * h2f((unsigned short)(u1 & 0xffff));
                        c1 += w2 * h2f((unsigned short)(u1 >> 16));
                    }
                    cv[g2][0] = c0; cv[g2][1] = c1;
                }
                cgp0[gp] = pack2h(cv[0][0], cv[1][0]);
                cgp1[gp] = pack2h(cv[0][1], cv[1][1]);
            }
            int q = q0 + ql, k = k0 + kb;
            bool val0 = (k <= q) && (k < kend);
            bool val1 = (k + 1 <= q) && (k + 1 < kend);
#pragma unroll
            for (int ff = 0; ff < 16; ++ff) {
                float s0 = 0.f, s1 = 0.f;
#pragma unroll
                for (int j = 0; j < 8; ++j) {
                    unsigned int w = wposmp[ff][j];
                    s0 = fdot2f(w, cgp0[j], s0);
                    s1 = fdot2f(w, cgp1[j], s1);
                }
                *(unsigned int*)&pm2[ff][ql][kb] = pack2h(val0 ? s0 : 0.f, val1 ? s1 : 0.f);
            }
        }
        __syncthreads();  // barB: pm2 ready

        // MFMA PV: wave wv handles heads wv*4..wv*4+3; B-frags direct from global vt
#pragma unroll
        for (int hh = 0; hh < 4; ++hh) {
            int f = wv * 4 + hh;
            f16x8 a = *(const f16x8*)&pm2[f][lr][lk * 8];
#pragma unroll
            for (int tc = 0; tc < 4; ++tc) {
                uint4 braw = *(const uint4*)
                    &vt[((size_t)(f * D + tc * 16 + lr)) * S + k0 + lk * 8];
                f16x8 b;
                __builtin_memcpy(&b, &braw, 16);
                acc[hh][tc] = __builtin_amdgcn_mfma_f32_16x16x32_f16(a, b, acc[hh][tc], 0, 0, 0);
            }
        }
        // next iteration's barA orders MFMA pm2-reads vs next conv writes
    }

    // epilogue: one atomicAdd pass
#pragma unroll
    for (int hh = 0; hh < 4; ++hh) {
        int f = wv * 4 + hh;
#pragma unroll
        for (int tc = 0; tc < 4; ++tc) {
#pragma unroll
            for (int i = 0; i < 4; ++i) {
                int q = q0 + lk * 4 + i;
                int d = tc * 16 + lr;
                atomicAdd(&out[((size_t)q * H + f) * D + d], acc[hh][tc][i]);
            }
        }
    }
}

// ===========================================================================
// Fallback path (round-2 kernels, verbatim): used when ws_size is too small.
// ===========================================================================
__global__ __launch_bounds__(256) void fb_stats_kernel(
        const float* __restrict__ xq, const float* __restrict__ xk,
        const float* __restrict__ w_pre, const float* __restrict__ w_psm,
        float* __restrict__ mpart, float* __restrict__ lpart) {
    const int kc = blockIdx.x, qt = blockIdx.y;
    const int q0 = qt * 16;
    const int kstart = kc * 256;
    if (kstart > q0 + 15) return;
    const int kend = min(kstart + 256, q0 + 16);
    const int tid = threadIdx.x;

    __shared__ unsigned short Qs[2][32][72];
    __shared__ unsigned short Ks[2][48][72];
    __shared__ float raws[32][50];
    __shared__ float wpre_s[16 * 66];
    __shared__ float wpsm_s[256];

    for (int i = tid; i < 16 * 66; i += 256) wpre_s[i] = w_pre[i];
    wpsm_s[tid] = w_psm[tid];

    const int ql = tid >> 4;
    const int kb = (tid & 15) * 2;
    const int q = q0 + ql;

    float mreg[16], lreg[16];
#pragma unroll
    for (int g = 0; g < 16; ++g) { mreg[g] = -INFINITY; lreg[g] = 0.f; }

    for (int k0 = kstart; k0 < kend; k0 += 32) {
        float acc0[16], acc1[16];
#pragma unroll
        for (int g = 0; g < 16; ++g) { acc0[g] = 0.f; acc1[g] = 0.f; }

        for (int h = 0; h < H; ++h) {
            {
                int r = tid >> 3, d = (tid & 7) * 8;
                int qp = q0 - 5 + r;
                float4 a = {0,0,0,0}, b = {0,0,0,0};
                if (r < 21 && qp >= 0) {
                    const float* p = &xq[(h * S + qp) * D + d];
                    a = *(const float4*)p; b = *(const float4*)(p + 4);
                }
                uint4 vh, vl; stage_hilo(a, b, &vh, &vl);
                *(uint4*)&Qs[0][r][d] = vh;
                *(uint4*)&Qs[1][r][d] = vl;
            }
            for (int i = tid; i < 384; i += 256) {
                int r = i >> 3, d = (i & 7) * 8;
                int kp = k0 - 10 + r;
                float4 a = {0,0,0,0}, b = {0,0,0,0};
                if (r < 42 && kp >= 0) {
                    const float* p = &xk[(h * S + kp) * D + d];
                    a = *(const float4*)p; b = *(const float4*)(p + 4);
                }
                uint4 vh, vl; stage_hilo(a, b, &vh, &vl);
                *(uint4*)&Ks[0][r][d] = vh;
                *(uint4*)&Ks[1][r][d] = vl;
            }
            __syncthreads();
            {
                int w = tid >> 6, l = tid & 63;
                int lr = l & 15, lk = l >> 4;
                for (int t = w; t < 6; t += 4) {
                    int tr = t / 3, tc = t % 3;
                    f32x4 acc = {0.f, 0.f, 0.f, 0.f};
#pragma unroll
                    for (int ks = 0; ks < 2; ++ks) {
                        int db = ks * 32 + lk * 8;
                        bf16x8 ah = *(const bf16x8*)&Qs[0][tr * 16 + lr][db];
                        bf16x8 al = *(const bf16x8*)&Qs[1][tr * 16 + lr][db];
                        bf16x8 bh = *(const bf16x8*)&Ks[0][tc * 16 + lr][db];
                        bf16x8 bl = *(const bf16x8*)&Ks[1][tc * 16 + lr][db];
                        acc = __builtin_amdgcn_mfma_f32_16x16x32_bf16(ah, bh, acc, 0, 0, 0);
                        acc = __builtin_amdgcn_mfma_f32_16x16x32_bf16(ah, bl, acc, 0, 0, 0);
                        acc = __builtin_amdgcn_mfma_f32_16x16x32_bf16(al, bh, acc, 0, 0, 0);
                    }
#pragma unroll
                    for (int i = 0; i < 4; ++i) {
                        int row = tr * 16 + lk * 4 + i;
                        int col = tc * 16 + lr;
                        int qp = q0 - 5 + row, kp = k0 - 10 + col;
                        raws[row][col] = (kp >= 0 && kp <= qp) ? acc[i] * SCALEQK : 0.f;
                    }
                }
            }
            __syncthreads();
            {
                float c0 = 0.f, c1 = 0.f;
#pragma unroll
                for (int i2 = 0; i2 < 6; ++i2) {
                    const float* rp = &raws[ql + i2][kb];
                    float v[12];
#pragma unroll
                    for (int j = 0; j < 6; ++j) {
                        float2 t = *(const float2*)(rp + 2 * j);
                        v[2 * j] = t.x; v[2 * j + 1] = t.y;
                    }
                    const float* wp = &wpre_s[h * 66 + i2 * 11];
#pragma unroll
                    for (int j = 0; j < 11; ++j) { c0 += wp[j] * v[j]; c1 += wp[j] * v[j + 1]; }
                }
#pragma unroll
                for (int g = 0; g < 16; ++g) {
                    float wg = wpsm_s[g * 16 + h];
                    acc0[g] += wg * c0; acc1[g] += wg * c1;
                }
            }
        }
        int kk = k0 + kb;
#pragma unroll
        for (int g = 0; g < 16; ++g) {
            if (kk <= q)     online_upd(mreg[g], lreg[g], acc0[g]);
            if (kk + 1 <= q) online_upd(mreg[g], lreg[g], acc1[g]);
        }
    }
#pragma unroll
    for (int g = 0; g < 16; ++g) {
        float m = mreg[g], l = lreg[g];
#pragma unroll
        for (int off = 1; off < 16; off <<= 1) {
            float m2 = __shfl_xor(m, off);
            float l2 = __shfl_xor(l, off);
            float nm = fmaxf(m, m2);
            float t1 = (l  > 0.f) ? l  * __expf(m  - nm) : 0.f;
            float t2 = (l2 > 0.f) ? l2 * __expf(m2 - nm) : 0.f;
            m = nm; l = t1 + t2;
        }
        if ((tid & 15) == 0) {
            mpart[((size_t)kc * H + g) * S + q] = m;
            lpart[((size_t)kc * H + g) * S + q] = l;
        }
    }
}

__global__ __launch_bounds__(256) void fb_reduce_kernel(
        const float* __restrict__ mpart, const float* __restrict__ lpart,
        float* __restrict__ mrow, float* __restrict__ rlrow) {
    int r = blockIdx.x * 256 + threadIdx.x;
    if (r >= H * S) return;
    int q = r & (S - 1);
    int nkc = (q >> 8) + 1;
    float m = -INFINITY;
    for (int kc = 0; kc < nkc; ++kc) m = fmaxf(m, mpart[(size_t)kc * H * S + r]);
    float l = 0.f;
    for (int kc = 0; kc < nkc; ++kc) {
        float li = lpart[(size_t)kc * H * S + r];
        float mi = mpart[(size_t)kc * H * S + r];
        if (li > 0.f) l += li * __expf(mi - m);
    }
    mrow[r] = m;
    rlrow[r] = 1.f / l;
}

__global__ __launch_bounds__(256) void fb_out_kernel(
        const float* __restrict__ xq, const float* __restrict__ xk,
        const float* __restrict__ xv,
        const float* __restrict__ w_pre, const float* __restrict__ w_psm,
        const float* __restrict__ w_post, const float* __restrict__ w_posm,
        const float* __restrict__ mrow, const float* __restrict__ rlrow,
        float* __restrict__ out) {
    const int qt = blockIdx.x, kc = blockIdx.y;
    const int q0 = qt * 8;
    const int kstart = kc * 256;
    if (kstart > q0 + 7) return;
    const int kend = min(kstart + 256, q0 + 8);
    const int tid = threadIdx.x;

    __shared__ unsigned short Qs[2][16][72];
    __shared__ unsigned short Ks[2][48][72];
    __shared__ float raws[16][50];
    __shared__ float ps[8][10][35];
    __shared__ float m2s[16][8][33];
    __shared__ float mst[16][10], rst[16][10];
    __shared__ float wpre_s[16 * 66], wpsm_s[256], wpost_s[144], wposm_s[256];

    for (int i = tid; i < 16 * 66; i += 256) wpre_s[i] = w_pre[i];
    wpsm_s[tid] = w_psm[tid];
    wposm_s[tid] = w_posm[tid];
    if (tid < 144) wpost_s[tid] = w_post[tid];
    for (int i = tid; i < 160; i += 256) {
        int g = i / 10, r = i % 10;
        int qp = q0 - 2 + r;
        if (qp >= 0) { mst[g][r] = mrow[g * S + qp]; rst[g][r] = rlrow[g * S + qp]; }
        else         { mst[g][r] = 0.f; rst[g][r] = 0.f; }
    }

    const int f = tid >> 4, qloc = (tid >> 1) & 7, dh = tid & 1;
    const int cr = tid / 17, cc = (tid % 17) * 2;
    const bool cvalid = tid < 170;
    const int ql2 = tid >> 5, kl = tid & 31;

    float oacc[32];
#pragma unroll
    for (int i = 0; i < 32; ++i) oacc[i] = 0.f;

    for (int k0 = kstart; k0 < kend; k0 += 32) {
        float a0[16], a1[16];
#pragma unroll
        for (int g = 0; g < 16; ++g) { a0[g] = 0.f; a1[g] = 0.f; }

        for (int h = 0; h < H; ++h) {
            if (tid < 128) {
                int r = tid >> 3, d = (tid & 7) * 8;
                int qp = q0 - 7 + r;
                float4 a = {0,0,0,0}, b = {0,0,0,0};
                if (qp >= 0 && qp < S) {
                    const float* p = &xq[(h * S + qp) * D + d];
                    a = *(const float4*)p; b = *(const float4*)(p + 4);
                }
                uint4 vh, vl; stage_hilo(a, b, &vh, &vl);
                *(uint4*)&Qs[0][r][d] = vh;
                *(uint4*)&Qs[1][r][d] = vl;
            }
            for (int i = tid; i < 384; i += 256) {
                int r = i >> 3, d = (i & 7) * 8;
                int kp = k0 - 12 + r;
                float4 a = {0,0,0,0}, b = {0,0,0,0};
                if (kp >= 0 && kp < S) {
                    const float* p = &xk[(h * S + kp) * D + d];
                    a = *(const float4*)p; b = *(const float4*)(p + 4);
                }
                uint4 vh, vl; stage_hilo(a, b, &vh, &vl);
                *(uint4*)&Ks[0][r][d] = vh;
                *(uint4*)&Ks[1][r][d] = vl;
            }
            __syncthreads();
            {
                int w = tid >> 6, l = tid & 63;
                int lr = l & 15, lk = l >> 4;
                if (w < 3) {
                    int tc = w;
                    f32x4 acc = {0.f, 0.f, 0.f, 0.f};
#pragma unroll
                    for (int ks = 0; ks < 2; ++ks) {
                        int db = ks * 32 + lk * 8;
                        bf16x8 ah = *(const bf16x8*)&Qs[0][lr][db];
                        bf16x8 al = *(const bf16x8*)&Qs[1][lr][db];
                        bf16x8 bh = *(const bf16x8*)&Ks[0][tc * 16 + lr][db];
                        bf16x8 bl = *(const bf16x8*)&Ks[1][tc * 16 + lr][db];
                        acc = __builtin_amdgcn_mfma_f32_16x16x32_bf16(ah, bh, acc, 0, 0, 0);
                        acc = __builtin_amdgcn_mfma_f32_16x16x32_bf16(ah, bl, acc, 0, 0, 0);
                        acc = __builtin_amdgcn_mfma_f32_16x16x32_bf16(al, bh, acc, 0, 0, 0);
                    }
#pragma unroll
                    for (int i = 0; i < 4; ++i) {
                        int row = lk * 4 + i, col = tc * 16 + lr;
                        int qp = q0 - 7 + row, kp = k0 - 12 + col;
                        raws[row][col] = (kp >= 0 && kp <= qp) ? acc[i] * SCALEQK : 0.f;
                    }
                }
            }
            __syncthreads();
            if (cvalid) {
                float c0 = 0.f, c1 = 0.f;
#pragma unroll
                for (int i2 = 0; i2 < 6; ++i2) {
                    const float* rp = &raws[cr + i2][cc];
                    float v[12];
#pragma unroll
                    for (int j = 0; j < 6; ++j) {
                        float2 t = *(const float2*)(rp + 2 * j);
                        v[2 * j] = t.x; v[2 * j + 1] = t.y;
                    }
                    const float* wp = &wpre_s[h * 66 + i2 * 11];
#pragma unroll
                    for (int j = 0; j < 11; ++j) { c0 += wp[j] * v[j]; c1 += wp[j] * v[j + 1]; }
                }
#pragma unroll
                for (int g = 0; g < 16; ++g) {
                    float wg = wpsm_s[g * 16 + h];
                    a0[g] += wg * c0; a1[g] += wg * c1;
                }
            }
        }

        float m2f[16];
#pragma unroll
        for (int i = 0; i < 16; ++i) m2f[i] = 0.f;

        for (int half = 0; half < 2; ++half) {
            if (cvalid) {
                int qp = q0 - 2 + cr;
                int kp0 = k0 - 2 + cc, kp1 = kp0 + 1;
#pragma unroll
                for (int g8 = 0; g8 < 8; ++g8) {
                    int g = half * 8 + g8;
                    float p0 = 0.f, p1 = 0.f;
                    if (qp >= 0) {
                        float mm = mst[g][cr], rr = rst[g][cr];
                        if (kp0 >= 0 && kp0 <= qp) p0 = __expf(a0[g] - mm) * rr;
                        if (kp1 >= 0 && kp1 <= qp) p1 = __expf(a1[g] - mm) * rr;
                    }
                    ps[g8][cr][cc] = p0;
                    ps[g8][cr][cc + 1] = p1;
                }
            }
            __syncthreads();
            {
                float cg[8];
#pragma unroll
                for (int g8 = 0; g8 < 8; ++g8) {
                    float c = 0.f;
#pragma unroll
                    for (int i2 = 0; i2 < 3; ++i2)
#pragma unroll
                        for (int j2 = 0; j2 < 3; ++j2)
                            c += wpost_s[(half * 8 + g8) * 9 + i2 * 3 + j2] * ps[g8][ql2 + i2][kl + j2];
                    cg[g8] = c;
                }
#pragma unroll
                for (int ff = 0; ff < 16; ++ff) {
                    float s = 0.f;
#pragma unroll
                    for (int g8 = 0; g8 < 8; ++g8) s += wposm_s[ff * 16 + half * 8 + g8] * cg[g8];
                    m2f[ff] += s;
                }
            }
            if (half == 0) __syncthreads();
        }
        {
            int q = q0 + ql2, k = k0 + kl;
            bool valid = (k <= q) && (k < kend);
#pragma unroll
            for (int ff = 0; ff < 16; ++ff) m2s[ff][ql2][kl] = valid ? m2f[ff] : 0.f;
        }
        __syncthreads();
        for (int kl2 = 0; kl2 < 32; ++kl2) {
            int k = k0 + kl2;
            if (k >= kend) break;
            float s = m2s[f][qloc][kl2];
            if (s != 0.f) {
                const float* vp = &xv[(f * S + k) * D + dh * 32];
#pragma unroll
                for (int d4 = 0; d4 < 8; ++d4) {
                    float4 v = *(const float4*)(vp + d4 * 4);
                    oacc[d4 * 4 + 0] += s * v.x;
                    oacc[d4 * 4 + 1] += s * v.y;
                    oacc[d4 * 4 + 2] += s * v.z;
                    oacc[d4 * 4 + 3] += s * v.w;
                }
            }
        }
        __syncthreads();
    }

    int q = q0 + qloc;
    float* op = out + ((size_t)q * H + f) * D + dh * 32;
#pragma unroll
    for (int i = 0; i < 32; ++i) atomicAdd(op + i, oacc[i]);
}

// ===========================================================================
extern "C" void kernel_launch(void* const* d_in, const int* in_sizes, int n_in,
                              void* d_out, int out_size, void* d_ws, size_t ws_size,
                              hipStream_t stream) {
    const float* xq     = (const float*)d_in[0];
    const float* xk     = (const float*)d_in[1];
    const float* xv     = (const float*)d_in[2];
    const float* w_pre  = (const float*)d_in[4];
    const float* w_post = (const float*)d_in[5];
    const float* w_psm  = (const float*)d_in[6];
    const float* w_posm = (const float*)d_in[7];
    float* out = (float*)d_out;

    hipMemsetAsync(d_out, 0, sizeof(float) * (size_t)out_size, stream);

    const size_t qkb   = (size_t)H * S * D * 2;   // 4 MiB per hi/lo array
    const size_t vtb   = (size_t)H * D * S * 2;   // 4 MiB
    const size_t statb = (size_t)H * S * 4;       // 128 KiB
    const size_t base  = 4 * qkb + vtb + 2 * statb;

    int SQ = 0;
    const int cands[5] = {2048, 1024, 512, 256, 128};
    for (int c = 0; c < 5; ++c) {
        size_t rb  = (size_t)H * (cands[c] + 64) * S * 2;
        size_t scb = (size_t)H * (cands[c] + 16) * S * 2 + 128;
        if (base + rb + scb <= ws_size) { SQ = cands[c]; break; }
    }

    if (SQ == 0) {
        float* mpart = (float*)d_ws;
        float* lpart = mpart + (size_t)8 * H * S;
        float* mrow  = lpart + (size_t)8 * H * S;
        float* rlrow = mrow + (size_t)H * S;
        dim3 g1(8, 128);
        fb_stats_kernel<<<g1, 256, 0, stream>>>(xq, xk, w_pre, w_psm, mpart, lpart);
        fb_reduce_kernel<<<128, 256, 0, stream>>>(mpart, lpart, mrow, rlrow);
        dim3 g2(256, 8);
        fb_out_kernel<<<g2, 256, 0, stream>>>(xq, xk, xv, w_pre, w_psm, w_post, w_posm,
                                              mrow, rlrow, out);
        return;
    }

    char* p = (char*)d_ws;
    unsigned short* qhi = (unsigned short*)p;            p += qkb;
    unsigned short* qlo = (unsigned short*)p;            p += qkb;
    unsigned short* khi = (unsigned short*)p;            p += qkb;
    unsigned short* klo = (unsigned short*)p;            p += qkb;
    unsigned short* vt  = (unsigned short*)p;            p += vtb;
    float* mrow  = (float*)p;                            p += statb;
    float* rlrow = (float*)p;                            p += statb;
    unsigned short* Rbuf = (unsigned short*)p;           p += (size_t)H * (SQ + 64) * S * 2;
    unsigned short* sc   = (unsigned short*)p;

    const int n8 = H * S * D / 8;
    mta_cvt_kernel<<<512, 256, 0, stream>>>(xq, qhi, qlo, SCALEQK, n8);
    mta_cvt_kernel<<<512, 256, 0, stream>>>(xk, khi, klo, 1.0f, n8);
    dim3 gv(S / 64, H);
    mta_vt_kernel<<<gv, 256, 0, stream>>>(xv, vt);

    for (int qs = 0; qs < S; qs += SQ) {
        dim3 gg(S / 64, SQ / 64 + 1, H);
        mta_gemm_kernel<<<gg, 256, 0, stream>>>(qhi, qlo, khi, klo, Rbuf, qs, SQ);
        dim3 gc(S / 64, SQ / 16 + 1);
        mta_convmix_kernel<<<gc, 256, 0, stream>>>(Rbuf, w_pre, w_psm, sc, qs, SQ);
        mta_rowstats_kernel<<<4 * SQ, 256, 0, stream>>>(sc, mrow, rlrow, qs, SQ);
        dim3 g2(SQ / 16, S / CH);
        mta_out2_kernel<<<g2, 256, 0, stream>>>(sc, mrow, rlrow, vt, w_post, w_posm,
                                                out, qs, SQ);
    }
}